// Round 10
// baseline (289.979 us; speedup 1.0000x reference)
//
#include <hip/hip_runtime.h>

#define D 128
#define RS 16     // readout sub-blocks per graph
#define NBMAX 1024  // max dst-buckets (64 nodes each); N<=65536 also required (src packs in 16 bits)
constexpr float EPS = 1e-5f;

typedef short bf16x8 __attribute__((ext_vector_type(8)));
typedef float f32x4 __attribute__((ext_vector_type(4)));

__device__ __forceinline__ uint f2bf(float f) {  // RNE f32->bf16 (finite inputs)
  union { float f; uint u; } v; v.f = f;
  return (v.u + 0x7fffu + ((v.u >> 16) & 1u)) >> 16;
}
__device__ __forceinline__ float bflo(uint u) {
  union { uint u; float f; } v; v.u = u << 16; return v.f;
}
__device__ __forceinline__ float bfhi(uint u) {
  union { uint u; float f; } v; v.u = u & 0xffff0000u; return v.f;
}

__device__ __forceinline__ int lower_bound(const int* __restrict__ a, int n, int key) {
  int lo = 0, hi = n;
  while (lo < hi) { int m = (lo + hi) >> 1; if (a[m] < key) lo = m + 1; else hi = m; }
  return lo;
}

// ---------- A: fused preprocessing ----------
// blocks [0,ebA): ocnt global atomics (0.8M, the floor) + LDS dst-bucket histogram
// blocks [ebA,ebA+cb): x -> bf16   |   blocks [ebA+cb, +24): W -> frag layout
__global__ __launch_bounds__(256) void k_pre(
    const int* __restrict__ src, const int* __restrict__ dst,
    int* __restrict__ ocnt, int* __restrict__ hist, int E, int nb, int ebA,
    const float4* __restrict__ x, uint4* __restrict__ xb, int n8, int cb,
    const float* __restrict__ W1, const float* __restrict__ W2,
    const float* __restrict__ W3, ushort* __restrict__ Wf) {
  __shared__ int hloc[NBMAX];
  int bid = blockIdx.x;
  int tid = threadIdx.x;
  if (bid < ebA) {
    for (int j = tid; j < nb; j += 256) hloc[j] = 0;
    __syncthreads();
    int e0 = bid * 4096;
#pragma unroll 4
    for (int it = 0; it < 16; ++it) {
      int e = e0 + it * 256 + tid;
      if (e < E) {
        atomicAdd(&ocnt[src[e]], 1);
        atomicAdd(&hloc[dst[e] >> 6], 1);
      }
    }
    __syncthreads();
    for (int j = tid; j < nb; j += 256) hist[bid * nb + j] = hloc[j];
  } else if (bid < ebA + cb) {
    int i = (bid - ebA) * 256 + tid;
    if (i < n8) {
      float4 p = x[i * 2], q = x[i * 2 + 1];
      uint4 o;
      o.x = f2bf(p.x) | (f2bf(p.y) << 16);
      o.y = f2bf(p.z) | (f2bf(p.w) << 16);
      o.z = f2bf(q.x) | (f2bf(q.y) << 16);
      o.w = f2bf(q.z) | (f2bf(q.w) << 16);
      xb[i] = o;
    }
  } else {
    // W frag layout: frag (ks,ct), lane l holds B[k][col]: k=ks*32+(l>>4)*8+j, col=ct*16+(l&15)
    int t4 = (bid - ebA - cb) * 256 + tid;
    if (t4 < 3 * 2048) {
      const float* Wsrc = (t4 < 2048) ? W1 : (t4 < 4096) ? W2 : W3;
      int t = t4 & 2047;
      int lane = t & 63;
      int frag = t >> 6;
      int ks = frag >> 3, ct = frag & 7;
      int col = ct * 16 + (lane & 15);
      int kb = ks * 32 + (lane >> 4) * 8;
      uint p[8];
#pragma unroll
      for (int j = 0; j < 8; ++j) p[j] = f2bf(Wsrc[(kb + j) * D + col]);
      uint4 o;
      o.x = p[0] | (p[1] << 16);
      o.y = p[2] | (p[3] << 16);
      o.z = p[4] | (p[5] << 16);
      o.w = p[6] | (p[7] << 16);
      *(uint4*)(Wf + (size_t)t4 * 8) = o;
    }
  }
}

// ---------- out-norm from ocnt ----------
__global__ void k_onorm(const int* __restrict__ ocnt, float* __restrict__ outn, int N) {
  int n = blockIdx.x * 256 + threadIdx.x;
  if (n < N) outn[n] = rsqrtf(fmaxf((float)ocnt[n], 1.0f));
}

// ---------- B: column-scan hist matrix -> absolute per-(block,bucket) offsets ----------
__global__ __launch_bounds__(1024) void k_bscan(int* __restrict__ hist,
                                                int* __restrict__ bb,
                                                int* __restrict__ rowptr,
                                                int nb, int ebA, int E, int N) {
  __shared__ int part[1024];
  int t = threadIdx.x;
  int s = 0;
  if (t < nb)
    for (int blk = 0; blk < ebA; ++blk) s += hist[blk * nb + t];
  part[t] = s;
  __syncthreads();
  for (int off = 1; off < 1024; off <<= 1) {
    int v = (t >= off) ? part[t - off] : 0;
    __syncthreads();
    part[t] += v;
    __syncthreads();
  }
  int excl = (t == 0) ? 0 : part[t - 1];
  if (t < nb) {
    bb[t] = excl;
    int run = excl;
    for (int blk = 0; blk < ebA; ++blk) {
      int h0 = hist[blk * nb + t];
      hist[blk * nb + t] = run;
      run += h0;
    }
  }
  if (t == 0) { bb[nb] = E; rowptr[N] = E; }
}

// ---------- C: scatter edges into bucket regions (packed u64) ----------
// pack: [63:32] coef bits (mean(w)*0.25*outn[src]), [21:16] dst&63, [15:0] src
__global__ __launch_bounds__(256) void k_bscatter(
    const int* __restrict__ src, const int* __restrict__ dst,
    const float4* __restrict__ w, const float* __restrict__ outn,
    const int* __restrict__ hist, unsigned long long* __restrict__ ebuf,
    int E, int nb) {
  __shared__ int curb[NBMAX];
  int bid = blockIdx.x, tid = threadIdx.x;
  for (int j = tid; j < nb; j += 256) curb[j] = hist[bid * nb + j];
  __syncthreads();
  int e0 = bid * 4096;
#pragma unroll 4
  for (int it = 0; it < 16; ++it) {
    int e = e0 + it * 256 + tid;
    if (e < E) {
      int d = dst[e], s = src[e];
      int pos = atomicAdd(&curb[d >> 6], 1);
      float4 wv = w[e];
      float coef = (wv.x + wv.y + wv.z + wv.w) * 0.25f * outn[s];
      unsigned long long pk = ((unsigned long long)__float_as_uint(coef) << 32) |
                              ((unsigned long long)(d & 63) << 16) | (uint)s;
      ebuf[pos] = pk;
    }
  }
}

// ---------- D: per-bucket count -> innm+rowptr (non-atomic) + final CSR place ----------
__global__ __launch_bounds__(256) void k_bplace(
    const unsigned long long* __restrict__ ebuf, const int* __restrict__ bb,
    int* __restrict__ rowptr, float* __restrict__ innm,
    int* __restrict__ src_p, float* __restrict__ coef_p, int N) {
  __shared__ int c64[64], ex[64], cur[64];
  int b = blockIdx.x, tid = threadIdx.x;
  int base = bb[b];
  int cnt = bb[b + 1] - base;
  if (tid < 64) c64[tid] = 0;
  __syncthreads();
  for (int i = tid; i < cnt; i += 256) {
    unsigned long long v = ebuf[base + i];
    atomicAdd(&c64[(int)((v >> 16) & 63)], 1);
  }
  __syncthreads();
  if (tid < 64) {  // wave 0: scan 64 counts
    int cv = c64[tid];
    int inc = cv;
#pragma unroll
    for (int off = 1; off < 64; off <<= 1) {
      int u = __shfl_up(inc, off);
      if (tid >= off) inc += u;
    }
    int excl = inc - cv;
    ex[tid] = excl;
    cur[tid] = 0;
    int node = b * 64 + tid;
    if (node < N) {
      rowptr[node] = base + excl;
      innm[node] = rsqrtf(fmaxf((float)cv, 1.0f));
    }
  }
  __syncthreads();
  for (int i = tid; i < cnt; i += 256) {
    unsigned long long v = ebuf[base + i];
    int dl = (int)((v >> 16) & 63);
    int pos = base + ex[dl] + atomicAdd(&cur[dl], 1);
    src_p[pos] = (int)(v & 0xFFFFu);
    coef_p[pos] = __uint_as_float((uint)(v >> 32));
  }
}

// ---------- FUSED layer: gather -> MFMA GEMM -> (ReLU+LN | f32 out) ----------
__global__ __launch_bounds__(256) void k_fused(
    const ushort* __restrict__ h, const int* __restrict__ rowptr,
    const int* __restrict__ src_p, const float* __restrict__ coef_p,
    const float* __restrict__ innm, const ushort* __restrict__ Wf,
    const float* __restrict__ g, const float* __restrict__ bta,
    void* __restrict__ out, int N, int do_ln) {
  __shared__ float lds[4][16 * D];  // 8 KiB per wave (A-tile, then epilogue)
  const int lane = threadIdx.x & 63;
  const int wv = threadIdx.x >> 6;
  const int row0 = blockIdx.x * 64 + wv * 16;
  if (row0 >= N) return;

  // ---- phase A: gather 16 rows into LDS tile [16][136]
  ushort* at = (ushort*)&lds[wv][0];
  {
    const int grp = lane >> 4;
    const int c = lane & 15;
    for (int rr = 0; rr < 4; ++rr) {
      int n = row0 + grp * 4 + rr;
      if (n >= N) break;
      int beg = rowptr[n], end = rowptr[n + 1];
      float a0 = 0, a1 = 0, a2 = 0, a3 = 0, a4 = 0, a5 = 0, a6 = 0, a7 = 0;
#define ACC8(q, f)                                          \
  a0 = fmaf(bflo(q.x), f, a0); a1 = fmaf(bfhi(q.x), f, a1); \
  a2 = fmaf(bflo(q.y), f, a2); a3 = fmaf(bfhi(q.y), f, a3); \
  a4 = fmaf(bflo(q.z), f, a4); a5 = fmaf(bfhi(q.z), f, a5); \
  a6 = fmaf(bflo(q.w), f, a6); a7 = fmaf(bfhi(q.w), f, a7);
      int j = beg;
      for (; j + 4 <= end; j += 4) {
        int s0 = src_p[j], s1 = src_p[j + 1], s2 = src_p[j + 2], s3 = src_p[j + 3];
        float f0 = coef_p[j], f1 = coef_p[j + 1], f2 = coef_p[j + 2], f3 = coef_p[j + 3];
        uint4 q0 = *(const uint4*)(h + (size_t)s0 * D + c * 8);
        uint4 q1 = *(const uint4*)(h + (size_t)s1 * D + c * 8);
        uint4 q2 = *(const uint4*)(h + (size_t)s2 * D + c * 8);
        uint4 q3 = *(const uint4*)(h + (size_t)s3 * D + c * 8);
        ACC8(q0, f0) ACC8(q1, f1) ACC8(q2, f2) ACC8(q3, f3)
      }
      for (; j < end; ++j) {
        int s = src_p[j];
        float f = coef_p[j];
        uint4 q = *(const uint4*)(h + (size_t)s * D + c * 8);
        ACC8(q, f)
      }
#undef ACC8
      float sc = innm[n];
      uint4 o;
      o.x = f2bf(a0 * sc) | (f2bf(a1 * sc) << 16);
      o.y = f2bf(a2 * sc) | (f2bf(a3 * sc) << 16);
      o.z = f2bf(a4 * sc) | (f2bf(a5 * sc) << 16);
      o.w = f2bf(a6 * sc) | (f2bf(a7 * sc) << 16);
      *(uint4*)(at + (grp * 4 + rr) * 136 + c * 8) = o;
    }
  }
  asm volatile("s_waitcnt lgkmcnt(0)" ::: "memory");
  __builtin_amdgcn_sched_barrier(0);

  // ---- phase B: MFMA from LDS A-tile
  const int lc = lane & 15, lg = lane >> 4;
  f32x4 acc[8];
#pragma unroll
  for (int ct = 0; ct < 8; ++ct) acc[ct] = (f32x4){0.f, 0.f, 0.f, 0.f};
#pragma unroll
  for (int ks = 0; ks < 4; ++ks) {
    bf16x8 a = *(const bf16x8*)(at + lc * 136 + ks * 32 + lg * 8);
    const ushort* wp = Wf + ((size_t)(ks * 8) * 64 + lane) * 8;
#pragma unroll
    for (int ct = 0; ct < 8; ++ct) {
      bf16x8 b = *(const bf16x8*)(wp + ct * 512);
      acc[ct] = __builtin_amdgcn_mfma_f32_16x16x32_bf16(a, b, acc[ct], 0, 0, 0);
    }
  }
  asm volatile("s_waitcnt lgkmcnt(0)" ::: "memory");
  __builtin_amdgcn_sched_barrier(0);

  if (do_ln) {
    float v[8][4];
#pragma unroll
    for (int ct = 0; ct < 8; ++ct)
#pragma unroll
      for (int j = 0; j < 4; ++j) v[ct][j] = fmaxf(acc[ct][j], 0.f);
    float mu[4], rs[4];
#pragma unroll
    for (int j = 0; j < 4; ++j) {
      float s = 0.f;
#pragma unroll
      for (int ct = 0; ct < 8; ++ct) s += v[ct][j];
#pragma unroll
      for (int off = 1; off < 16; off <<= 1) s += __shfl_xor(s, off);
      mu[j] = s * (1.0f / D);
    }
#pragma unroll
    for (int j = 0; j < 4; ++j) {
      float q = 0.f;
#pragma unroll
      for (int ct = 0; ct < 8; ++ct) {
        v[ct][j] -= mu[j];
        q = fmaf(v[ct][j], v[ct][j], q);
      }
#pragma unroll
      for (int off = 1; off < 16; off <<= 1) q += __shfl_xor(q, off);
      rs[j] = rsqrtf(q * (1.0f / D) + EPS);
    }
    ushort* lp = (ushort*)&lds[wv][0];
#pragma unroll
    for (int ct = 0; ct < 8; ++ct) {
      float gc = g[ct * 16 + lc], bc = bta[ct * 16 + lc];
#pragma unroll
      for (int j = 0; j < 4; ++j)
        lp[(lg * 4 + j) * D + ct * 16 + lc] = (ushort)f2bf(fmaf(v[ct][j] * rs[j], gc, bc));
    }
    __builtin_amdgcn_wave_barrier();
    int r = row0 + (lane >> 2);
    if (r < N) {
      ushort* ob = (ushort*)out + (size_t)row0 * D + lane * 32;
#pragma unroll
      for (int i = 0; i < 4; ++i)
        ((uint4*)ob)[i] = ((const uint4*)(lp + lane * 32))[i];
    }
  } else {
    float* lp = &lds[wv][0];
#pragma unroll
    for (int ct = 0; ct < 8; ++ct)
#pragma unroll
      for (int j = 0; j < 4; ++j)
        lp[(lg * 4 + j) * D + ct * 16 + lc] = acc[ct][j];
    __builtin_amdgcn_wave_barrier();
    int r = row0 + (lane >> 2);
    if (r < N) {
      float* ob = (float*)out + (size_t)row0 * D + lane * 32;
#pragma unroll
      for (int i = 0; i < 8; ++i)
        ((float4*)ob)[i] = ((const float4*)(lp + lane * 32))[i];
    }
  }
}

// ---------- readout stage 1: partial sums, RS blocks per graph ----------
__global__ __launch_bounds__(128) void k_rpart(
    const float* __restrict__ h, const int* __restrict__ gid,
    float* __restrict__ part, int N) {
  int b = blockIdx.x / RS, s = blockIdx.x % RS;
  int t = threadIdx.x;
  int start = lower_bound(gid, N, b);
  int end = lower_bound(gid, N, b + 1);
  int len = end - start;
  int chunk = (len + RS - 1) / RS;
  int rb = start + s * chunk;
  int re = min(rb + chunk, end);
  float acc = 0.f;
  for (int n = rb; n < re; ++n) acc += h[(size_t)n * D + t];
  part[((size_t)b * RS + s) * D + t] = acc;
}

// ---------- readout stage 2 ----------
__global__ __launch_bounds__(128) void k_rsum(
    const float* __restrict__ part, float* __restrict__ out) {
  int b = blockIdx.x;
  int t = threadIdx.x;
  float acc = 0.f;
#pragma unroll
  for (int s = 0; s < RS; ++s) acc += part[((size_t)b * RS + s) * D + t];
  out[(size_t)b * D + t] = acc;
}

extern "C" void kernel_launch(void* const* d_in, const int* in_sizes, int n_in,
                              void* d_out, int out_size, void* d_ws, size_t ws_size,
                              hipStream_t stream) {
  const float* x    = (const float*)d_in[0];
  const float* w    = (const float*)d_in[1];
  const float* W1   = (const float*)d_in[2];
  const float* W2   = (const float*)d_in[3];
  const float* W3   = (const float*)d_in[4];
  const float* ln1g = (const float*)d_in[5];
  const float* ln1b = (const float*)d_in[6];
  const float* ln2g = (const float*)d_in[7];
  const float* ln2b = (const float*)d_in[8];
  const int* src = (const int*)d_in[9];
  const int* dst = (const int*)d_in[10];
  const int* gid = (const int*)d_in[11];
  const int N = in_sizes[0] / D;
  const int E = in_sizes[9];
  const int B = out_size / D;
  float* outp = (float*)d_out;

  // workspace layout
  float*  h3f  = (float*)d_ws;                   // [N*D] f32 layer-3 out; ebuf aliases it
  ushort* xb   = (ushort*)(h3f + (size_t)N * D); // [N*D] bf16 (x, then h2)
  ushort* hb1  = xb + (size_t)N * D;             // [N*D] bf16 (h1)
  ushort* Wf   = hb1 + (size_t)N * D;            // [3*2048*8]
  float*  outn = (float*)(Wf + 3 * 2048 * 8);    // [N]
  float*  innm = outn + N;                       // [N]
  int*    ocnt = (int*)(innm + N);               // [N]
  int*    rowptr = ocnt + N;                     // [N+1]
  int*    src_p  = rowptr + N + 1;               // [E]
  float*  coef_p = (float*)(src_p + E);          // [E]
  const int nb  = (N + 63) >> 6;                 // dst buckets
  const int ebA = (E + 4095) / 4096;             // edge blocks (4096 edges each)
  int*    hist = (int*)(coef_p + E);             // [ebA*nb]
  int*    bb   = hist + ebA * nb;                // [nb+1]
  float*  part = (float*)(bb + nb + 1);          // [B*RS*D]
  unsigned long long* ebuf = (unsigned long long*)h3f;  // [E] aliases h3f

  const int mb  = (N + 63) / 64;
  const int n8  = N * D / 8;
  const int cb  = (n8 + 255) / 256;

  // ---- CSR build (bucketed, minimal global atomics) ----
  hipMemsetAsync(ocnt, 0, sizeof(int) * (size_t)N, stream);
  k_pre<<<ebA + cb + 24, 256, 0, stream>>>(src, dst, ocnt, hist, E, nb, ebA,
                                           (const float4*)x, (uint4*)xb, n8, cb,
                                           W1, W2, W3, Wf);
  k_onorm<<<(N + 255) / 256, 256, 0, stream>>>(ocnt, outn, N);
  k_bscan<<<1, 1024, 0, stream>>>(hist, bb, rowptr, nb, ebA, E, N);
  k_bscatter<<<ebA, 256, 0, stream>>>(src, dst, (const float4*)w, outn, hist, ebuf, E, nb);
  k_bplace<<<nb, 256, 0, stream>>>(ebuf, bb, rowptr, innm, src_p, coef_p, N);

  // ---- 3 fused layers ----
  k_fused<<<mb, 256, 0, stream>>>(xb, rowptr, src_p, coef_p, innm, Wf,
                                  ln1g, ln1b, hb1, N, 1);
  k_fused<<<mb, 256, 0, stream>>>(hb1, rowptr, src_p, coef_p, innm, Wf + 16384,
                                  ln2g, ln2b, xb, N, 1);
  k_fused<<<mb, 256, 0, stream>>>(xb, rowptr, src_p, coef_p, innm, Wf + 32768,
                                  nullptr, nullptr, h3f, N, 0);

  // ---- readout ----
  k_rpart<<<B * RS, 128, 0, stream>>>(h3f, gid, part, N);
  k_rsum<<<B, 128, 0, stream>>>(part, outp);
}

// Round 11
// 224.775 us; speedup vs baseline: 1.2901x; 1.2901x over previous
//
#include <hip/hip_runtime.h>

#define D 128
#define RS 16       // readout sub-blocks per graph
#define NBMAX 1024  // max dst-buckets (64 nodes each); also requires N<=65536 (src packs in 16 bits)
constexpr float EPS = 1e-5f;

typedef short bf16x8 __attribute__((ext_vector_type(8)));
typedef float f32x4 __attribute__((ext_vector_type(4)));

__device__ __forceinline__ uint f2bf(float f) {  // RNE f32->bf16 (finite inputs)
  union { float f; uint u; } v; v.f = f;
  return (v.u + 0x7fffu + ((v.u >> 16) & 1u)) >> 16;
}
__device__ __forceinline__ float bflo(uint u) {
  union { uint u; float f; } v; v.u = u << 16; return v.f;
}
__device__ __forceinline__ float bfhi(uint u) {
  union { uint u; float f; } v; v.u = u & 0xffff0000u; return v.f;
}

__device__ __forceinline__ int lower_bound(const int* __restrict__ a, int n, int key) {
  int lo = 0, hi = n;
  while (lo < hi) { int m = (lo + hi) >> 1; if (a[m] < key) lo = m + 1; else hi = m; }
  return lo;
}

// ---------- A: fused preprocessing ----------
// blocks [0,ebA): ocnt global atomics (0.8M, the floor) + LDS dst-bucket hist ->
//                 ONE atomicAdd per (block,bucket) into btot (<=153K extra atomics)
// blocks [ebA,ebA+cb): x -> bf16   |   blocks [ebA+cb, +24): W -> frag layout
__global__ __launch_bounds__(256) void k_pre(
    const int* __restrict__ src, const int* __restrict__ dst,
    int* __restrict__ ocnt, int* __restrict__ btot, int E, int nb, int ebA,
    const float4* __restrict__ x, uint4* __restrict__ xb, int n8, int cb,
    const float* __restrict__ W1, const float* __restrict__ W2,
    const float* __restrict__ W3, ushort* __restrict__ Wf) {
  __shared__ int hloc[NBMAX];
  int bid = blockIdx.x;
  int tid = threadIdx.x;
  if (bid < ebA) {
    for (int j = tid; j < nb; j += 256) hloc[j] = 0;
    __syncthreads();
    int e0 = bid * 4096;
#pragma unroll 4
    for (int it = 0; it < 16; ++it) {
      int e = e0 + it * 256 + tid;
      if (e < E) {
        atomicAdd(&ocnt[src[e]], 1);
        atomicAdd(&hloc[dst[e] >> 6], 1);
      }
    }
    __syncthreads();
    for (int j = tid; j < nb; j += 256) {
      int c = hloc[j];
      if (c) atomicAdd(&btot[j], c);
    }
  } else if (bid < ebA + cb) {
    int i = (bid - ebA) * 256 + tid;
    if (i < n8) {
      float4 p = x[i * 2], q = x[i * 2 + 1];
      uint4 o;
      o.x = f2bf(p.x) | (f2bf(p.y) << 16);
      o.y = f2bf(p.z) | (f2bf(p.w) << 16);
      o.z = f2bf(q.x) | (f2bf(q.y) << 16);
      o.w = f2bf(q.z) | (f2bf(q.w) << 16);
      xb[i] = o;
    }
  } else {
    // W frag layout: frag (ks,ct), lane l holds B[k][col]: k=ks*32+(l>>4)*8+j, col=ct*16+(l&15)
    int t4 = (bid - ebA - cb) * 256 + tid;
    if (t4 < 3 * 2048) {
      const float* Wsrc = (t4 < 2048) ? W1 : (t4 < 4096) ? W2 : W3;
      int t = t4 & 2047;
      int lane = t & 63;
      int frag = t >> 6;
      int ks = frag >> 3, ct = frag & 7;
      int col = ct * 16 + (lane & 15);
      int kb = ks * 32 + (lane >> 4) * 8;
      uint p[8];
#pragma unroll
      for (int j = 0; j < 8; ++j) p[j] = f2bf(Wsrc[(kb + j) * D + col]);
      uint4 o;
      o.x = p[0] | (p[1] << 16);
      o.y = p[2] | (p[3] << 16);
      o.z = p[4] | (p[5] << 16);
      o.w = p[6] | (p[7] << 16);
      *(uint4*)(Wf + (size_t)t4 * 8) = o;
    }
  }
}

// ---------- out-norm from ocnt ----------
__global__ void k_onorm(const int* __restrict__ ocnt, float* __restrict__ outn, int N) {
  int n = blockIdx.x * 256 + threadIdx.x;
  if (n < N) outn[n] = rsqrtf(fmaxf((float)ocnt[n], 1.0f));
}

// ---------- B: exclusive scan of bucket totals (nb <= 1024) ----------
__global__ __launch_bounds__(1024) void k_bbase(const int* __restrict__ btot,
                                                int* __restrict__ bb,
                                                int* __restrict__ rowptr,
                                                int nb, int E, int N) {
  __shared__ int part[1024];
  int t = threadIdx.x;
  int v = (t < nb) ? btot[t] : 0;
  part[t] = v;
  __syncthreads();
  for (int off = 1; off < 1024; off <<= 1) {
    int u = (t >= off) ? part[t - off] : 0;
    __syncthreads();
    part[t] += u;
    __syncthreads();
  }
  if (t < nb) bb[t] = part[t] - v;  // exclusive
  if (t == 0) { bb[nb] = E; rowptr[N] = E; }
}

// ---------- C: scatter edges into bucket regions via atomic range reservation ----------
// pack: [63:32] coef bits (mean(w)*0.25*outn[src]), [21:16] dst&63, [15:0] src
__global__ __launch_bounds__(256) void k_bscatter(
    const int* __restrict__ src, const int* __restrict__ dst,
    const float4* __restrict__ w, const float* __restrict__ outn,
    const int* __restrict__ bb, int* __restrict__ bcur,
    unsigned long long* __restrict__ ebuf, int E, int nb) {
  __shared__ int hloc[NBMAX];
  __shared__ int hcur[NBMAX];
  int bid = blockIdx.x, tid = threadIdx.x;
  for (int j = tid; j < nb; j += 256) hloc[j] = 0;
  __syncthreads();
  int e0 = bid * 4096;
#pragma unroll 4
  for (int it = 0; it < 16; ++it) {
    int e = e0 + it * 256 + tid;
    if (e < E) atomicAdd(&hloc[dst[e] >> 6], 1);
  }
  __syncthreads();
  for (int j = tid; j < nb; j += 256) {
    int c = hloc[j];
    hcur[j] = c ? (bb[j] + atomicAdd(&bcur[j], c)) : 0;  // reserve [base, base+c)
  }
  __syncthreads();
#pragma unroll 4
  for (int it = 0; it < 16; ++it) {
    int e = e0 + it * 256 + tid;
    if (e < E) {
      int d = dst[e], s = src[e];
      int pos = atomicAdd(&hcur[d >> 6], 1);
      float4 wv = w[e];
      float coef = (wv.x + wv.y + wv.z + wv.w) * 0.25f * outn[s];
      unsigned long long pk = ((unsigned long long)__float_as_uint(coef) << 32) |
                              ((unsigned long long)(d & 63) << 16) | (uint)s;
      ebuf[pos] = pk;
    }
  }
}

// ---------- D: per-bucket count -> innm+rowptr (non-atomic) + final CSR place ----------
__global__ __launch_bounds__(256) void k_bplace(
    const unsigned long long* __restrict__ ebuf, const int* __restrict__ bb,
    int* __restrict__ rowptr, float* __restrict__ innm,
    int* __restrict__ src_p, float* __restrict__ coef_p, int N) {
  __shared__ int c64[64], ex[64], cur[64];
  int b = blockIdx.x, tid = threadIdx.x;
  int base = bb[b];
  int cnt = bb[b + 1] - base;
  if (tid < 64) c64[tid] = 0;
  __syncthreads();
  for (int i = tid; i < cnt; i += 256) {
    unsigned long long v = ebuf[base + i];
    atomicAdd(&c64[(int)((v >> 16) & 63)], 1);
  }
  __syncthreads();
  if (tid < 64) {  // wave 0: scan 64 counts
    int cv = c64[tid];
    int inc = cv;
#pragma unroll
    for (int off = 1; off < 64; off <<= 1) {
      int u = __shfl_up(inc, off);
      if (tid >= off) inc += u;
    }
    int excl = inc - cv;
    ex[tid] = excl;
    cur[tid] = 0;
    int node = b * 64 + tid;
    if (node < N) {
      rowptr[node] = base + excl;
      innm[node] = rsqrtf(fmaxf((float)cv, 1.0f));
    }
  }
  __syncthreads();
  for (int i = tid; i < cnt; i += 256) {
    unsigned long long v = ebuf[base + i];
    int dl = (int)((v >> 16) & 63);
    int pos = base + ex[dl] + atomicAdd(&cur[dl], 1);
    src_p[pos] = (int)(v & 0xFFFFu);
    coef_p[pos] = __uint_as_float((uint)(v >> 32));
  }
}

// ---------- FUSED layer: gather -> MFMA GEMM -> (ReLU+LN | f32 out) ----------
__global__ __launch_bounds__(256) void k_fused(
    const ushort* __restrict__ h, const int* __restrict__ rowptr,
    const int* __restrict__ src_p, const float* __restrict__ coef_p,
    const float* __restrict__ innm, const ushort* __restrict__ Wf,
    const float* __restrict__ g, const float* __restrict__ bta,
    void* __restrict__ out, int N, int do_ln) {
  __shared__ float lds[4][16 * D];  // 8 KiB per wave (A-tile, then epilogue)
  const int lane = threadIdx.x & 63;
  const int wv = threadIdx.x >> 6;
  const int row0 = blockIdx.x * 64 + wv * 16;
  if (row0 >= N) return;

  // ---- phase A: gather 16 rows into LDS tile [16][136]
  ushort* at = (ushort*)&lds[wv][0];
  {
    const int grp = lane >> 4;
    const int c = lane & 15;
    for (int rr = 0; rr < 4; ++rr) {
      int n = row0 + grp * 4 + rr;
      if (n >= N) break;
      int beg = rowptr[n], end = rowptr[n + 1];
      float a0 = 0, a1 = 0, a2 = 0, a3 = 0, a4 = 0, a5 = 0, a6 = 0, a7 = 0;
#define ACC8(q, f)                                          \
  a0 = fmaf(bflo(q.x), f, a0); a1 = fmaf(bfhi(q.x), f, a1); \
  a2 = fmaf(bflo(q.y), f, a2); a3 = fmaf(bfhi(q.y), f, a3); \
  a4 = fmaf(bflo(q.z), f, a4); a5 = fmaf(bfhi(q.z), f, a5); \
  a6 = fmaf(bflo(q.w), f, a6); a7 = fmaf(bfhi(q.w), f, a7);
      int j = beg;
      for (; j + 4 <= end; j += 4) {
        int s0 = src_p[j], s1 = src_p[j + 1], s2 = src_p[j + 2], s3 = src_p[j + 3];
        float f0 = coef_p[j], f1 = coef_p[j + 1], f2 = coef_p[j + 2], f3 = coef_p[j + 3];
        uint4 q0 = *(const uint4*)(h + (size_t)s0 * D + c * 8);
        uint4 q1 = *(const uint4*)(h + (size_t)s1 * D + c * 8);
        uint4 q2 = *(const uint4*)(h + (size_t)s2 * D + c * 8);
        uint4 q3 = *(const uint4*)(h + (size_t)s3 * D + c * 8);
        ACC8(q0, f0) ACC8(q1, f1) ACC8(q2, f2) ACC8(q3, f3)
      }
      for (; j < end; ++j) {
        int s = src_p[j];
        float f = coef_p[j];
        uint4 q = *(const uint4*)(h + (size_t)s * D + c * 8);
        ACC8(q, f)
      }
#undef ACC8
      float sc = innm[n];
      uint4 o;
      o.x = f2bf(a0 * sc) | (f2bf(a1 * sc) << 16);
      o.y = f2bf(a2 * sc) | (f2bf(a3 * sc) << 16);
      o.z = f2bf(a4 * sc) | (f2bf(a5 * sc) << 16);
      o.w = f2bf(a6 * sc) | (f2bf(a7 * sc) << 16);
      *(uint4*)(at + (grp * 4 + rr) * 136 + c * 8) = o;
    }
  }
  asm volatile("s_waitcnt lgkmcnt(0)" ::: "memory");
  __builtin_amdgcn_sched_barrier(0);

  // ---- phase B: MFMA from LDS A-tile
  const int lc = lane & 15, lg = lane >> 4;
  f32x4 acc[8];
#pragma unroll
  for (int ct = 0; ct < 8; ++ct) acc[ct] = (f32x4){0.f, 0.f, 0.f, 0.f};
#pragma unroll
  for (int ks = 0; ks < 4; ++ks) {
    bf16x8 a = *(const bf16x8*)(at + lc * 136 + ks * 32 + lg * 8);
    const ushort* wp = Wf + ((size_t)(ks * 8) * 64 + lane) * 8;
#pragma unroll
    for (int ct = 0; ct < 8; ++ct) {
      bf16x8 b = *(const bf16x8*)(wp + ct * 512);
      acc[ct] = __builtin_amdgcn_mfma_f32_16x16x32_bf16(a, b, acc[ct], 0, 0, 0);
    }
  }
  asm volatile("s_waitcnt lgkmcnt(0)" ::: "memory");
  __builtin_amdgcn_sched_barrier(0);

  if (do_ln) {
    float v[8][4];
#pragma unroll
    for (int ct = 0; ct < 8; ++ct)
#pragma unroll
      for (int j = 0; j < 4; ++j) v[ct][j] = fmaxf(acc[ct][j], 0.f);
    float mu[4], rs[4];
#pragma unroll
    for (int j = 0; j < 4; ++j) {
      float s = 0.f;
#pragma unroll
      for (int ct = 0; ct < 8; ++ct) s += v[ct][j];
#pragma unroll
      for (int off = 1; off < 16; off <<= 1) s += __shfl_xor(s, off);
      mu[j] = s * (1.0f / D);
    }
#pragma unroll
    for (int j = 0; j < 4; ++j) {
      float q = 0.f;
#pragma unroll
      for (int ct = 0; ct < 8; ++ct) {
        v[ct][j] -= mu[j];
        q = fmaf(v[ct][j], v[ct][j], q);
      }
#pragma unroll
      for (int off = 1; off < 16; off <<= 1) q += __shfl_xor(q, off);
      rs[j] = rsqrtf(q * (1.0f / D) + EPS);
    }
    ushort* lp = (ushort*)&lds[wv][0];
#pragma unroll
    for (int ct = 0; ct < 8; ++ct) {
      float gc = g[ct * 16 + lc], bc = bta[ct * 16 + lc];
#pragma unroll
      for (int j = 0; j < 4; ++j)
        lp[(lg * 4 + j) * D + ct * 16 + lc] = (ushort)f2bf(fmaf(v[ct][j] * rs[j], gc, bc));
    }
    __builtin_amdgcn_wave_barrier();
    int r = row0 + (lane >> 2);
    if (r < N) {
      ushort* ob = (ushort*)out + (size_t)row0 * D + lane * 32;
#pragma unroll
      for (int i = 0; i < 4; ++i)
        ((uint4*)ob)[i] = ((const uint4*)(lp + lane * 32))[i];
    }
  } else {
    float* lp = &lds[wv][0];
#pragma unroll
    for (int ct = 0; ct < 8; ++ct)
#pragma unroll
      for (int j = 0; j < 4; ++j)
        lp[(lg * 4 + j) * D + ct * 16 + lc] = acc[ct][j];
    __builtin_amdgcn_wave_barrier();
    int r = row0 + (lane >> 2);
    if (r < N) {
      float* ob = (float*)out + (size_t)row0 * D + lane * 32;
#pragma unroll
      for (int i = 0; i < 8; ++i)
        ((float4*)ob)[i] = ((const float4*)(lp + lane * 32))[i];
    }
  }
}

// ---------- readout stage 1: partial sums, RS blocks per graph ----------
__global__ __launch_bounds__(128) void k_rpart(
    const float* __restrict__ h, const int* __restrict__ gid,
    float* __restrict__ part, int N) {
  int b = blockIdx.x / RS, s = blockIdx.x % RS;
  int t = threadIdx.x;
  int start = lower_bound(gid, N, b);
  int end = lower_bound(gid, N, b + 1);
  int len = end - start;
  int chunk = (len + RS - 1) / RS;
  int rb = start + s * chunk;
  int re = min(rb + chunk, end);
  float acc = 0.f;
  for (int n = rb; n < re; ++n) acc += h[(size_t)n * D + t];
  part[((size_t)b * RS + s) * D + t] = acc;
}

// ---------- readout stage 2 ----------
__global__ __launch_bounds__(128) void k_rsum(
    const float* __restrict__ part, float* __restrict__ out) {
  int b = blockIdx.x;
  int t = threadIdx.x;
  float acc = 0.f;
#pragma unroll
  for (int s = 0; s < RS; ++s) acc += part[((size_t)b * RS + s) * D + t];
  out[(size_t)b * D + t] = acc;
}

extern "C" void kernel_launch(void* const* d_in, const int* in_sizes, int n_in,
                              void* d_out, int out_size, void* d_ws, size_t ws_size,
                              hipStream_t stream) {
  const float* x    = (const float*)d_in[0];
  const float* w    = (const float*)d_in[1];
  const float* W1   = (const float*)d_in[2];
  const float* W2   = (const float*)d_in[3];
  const float* W3   = (const float*)d_in[4];
  const float* ln1g = (const float*)d_in[5];
  const float* ln1b = (const float*)d_in[6];
  const float* ln2g = (const float*)d_in[7];
  const float* ln2b = (const float*)d_in[8];
  const int* src = (const int*)d_in[9];
  const int* dst = (const int*)d_in[10];
  const int* gid = (const int*)d_in[11];
  const int N = in_sizes[0] / D;
  const int E = in_sizes[9];
  const int B = out_size / D;
  float* outp = (float*)d_out;

  // workspace layout
  float*  h3f  = (float*)d_ws;                   // [N*D] f32 layer-3 out; ebuf aliases it
  ushort* xb   = (ushort*)(h3f + (size_t)N * D); // [N*D] bf16 (x, then h2)
  ushort* hb1  = xb + (size_t)N * D;             // [N*D] bf16 (h1)
  ushort* Wf   = hb1 + (size_t)N * D;            // [3*2048*8]
  float*  outn = (float*)(Wf + 3 * 2048 * 8);    // [N]
  float*  innm = outn + N;                       // [N]
  const int nb  = (N + 63) >> 6;                 // dst buckets
  const int ebA = (E + 4095) / 4096;             // edge blocks (4096 edges each)
  int*    ocnt = (int*)(innm + N);               // [N]    -- memset region start
  int*    btot = ocnt + N;                       // [nb]
  int*    bcur = btot + nb;                      // [nb]   -- memset region end
  int*    rowptr = bcur + nb;                    // [N+1]
  int*    src_p  = rowptr + N + 1;               // [E]
  float*  coef_p = (float*)(src_p + E);          // [E]
  int*    bb   = (int*)(coef_p + E);             // [nb+1]
  float*  part = (float*)(bb + nb + 1);          // [B*RS*D]
  unsigned long long* ebuf = (unsigned long long*)h3f;  // [E] aliases h3f

  const int mb  = (N + 63) / 64;
  const int n8  = N * D / 8;
  const int cb  = (n8 + 255) / 256;

  // ---- CSR build (bucketed, reservation-based; no hist matrix, no serial scan) ----
  hipMemsetAsync(ocnt, 0, sizeof(int) * ((size_t)N + 2 * nb), stream);
  k_pre<<<ebA + cb + 24, 256, 0, stream>>>(src, dst, ocnt, btot, E, nb, ebA,
                                           (const float4*)x, (uint4*)xb, n8, cb,
                                           W1, W2, W3, Wf);
  k_onorm<<<(N + 255) / 256, 256, 0, stream>>>(ocnt, outn, N);
  k_bbase<<<1, 1024, 0, stream>>>(btot, bb, rowptr, nb, E, N);
  k_bscatter<<<ebA, 256, 0, stream>>>(src, dst, (const float4*)w, outn, bb, bcur,
                                      ebuf, E, nb);
  k_bplace<<<nb, 256, 0, stream>>>(ebuf, bb, rowptr, innm, src_p, coef_p, N);

  // ---- 3 fused layers ----
  k_fused<<<mb, 256, 0, stream>>>(xb, rowptr, src_p, coef_p, innm, Wf,
                                  ln1g, ln1b, hb1, N, 1);
  k_fused<<<mb, 256, 0, stream>>>(hb1, rowptr, src_p, coef_p, innm, Wf + 16384,
                                  ln2g, ln2b, xb, N, 1);
  k_fused<<<mb, 256, 0, stream>>>(xb, rowptr, src_p, coef_p, innm, Wf + 32768,
                                  nullptr, nullptr, h3f, N, 0);

  // ---- readout ----
  k_rpart<<<B * RS, 128, 0, stream>>>(h3f, gid, part, N);
  k_rsum<<<B, 128, 0, stream>>>(part, outp);
}